// Round 17
// baseline (84.889 us; speedup 1.0000x reference)
//
#include <hip/hip_runtime.h>

// Forward collapse:
//   c = y[b]; k = argmax_k(logits[c,k] + gumbel[c,b,k]) (first max)
//   x[b,:] = L[c,k] @ z[b,:] + m[c,k,:]
//
// Round 17: R16 structure (one kernel, zero cross-block communication) with
// NSL=2: grid (100 ck, 2 jh, 2 slices) = 400 blocks -> ALL blocks fit in one
// residency round (capacity 512 at launch_bounds(256,2), 18.4 KB LDS), vs
// R16's 800 blocks = 1.6 rounds. Per block: scan own 4096-sample slice
// (y coalesced 4 uint4/thr, gumbel gathered only for y==c, fp32-exact argmax),
// pitched Lsb bf16 (conflict-free), ONE barrier, mfma_f32_16x16x32_bf16,
// fp32 epilogue. Slices partition samples -> each output written exactly once.

#define N_Z 128
#define N_COMP 10
#define N_CLASSES 10
#define N_CK (N_CLASSES * N_COMP)
#define NSL 2            // sample slices
#define LPITCH 136       // bf16 per Lsb row (272 B; 68 dw = 4 mod 32 banks)
#define LIST_CAP 256

typedef __attribute__((ext_vector_type(4))) __bf16 bf16x4;
typedef __attribute__((ext_vector_type(8))) __bf16 bf16x8;
typedef __attribute__((ext_vector_type(4))) float f32x4;

__global__ __launch_bounds__(256, 2) void k_all(
    const float* __restrict__ z, const int* __restrict__ y,
    const float* __restrict__ gumbel, const float* __restrict__ m,
    const float* __restrict__ L, const float* __restrict__ logits,
    float* __restrict__ out, int bs)
{
    const int ck  = blockIdx.x;
    const int jh  = blockIdx.y;              // j range [jh*64, jh*64+64)
    const int slc = blockIdx.z;              // sample slice 0..1
    const int c   = ck / N_COMP;
    const int kk  = ck - c * N_COMP;
    const int t   = threadIdx.x;

    __shared__ __align__(16) __bf16 Lsb[64 * LPITCH];  // 17 KB pitched rows
    __shared__ int list[LIST_CAP];                     // 1 KB
    __shared__ int cnt;

    if (t == 0) cnt = 0;
    __syncthreads();   // cheap: nothing in flight yet

    // ---- prefetch L half into regs ----
    float4 lv[8];
    {
        const float4* Lg4 = (const float4*)(L + ((size_t)ck * N_Z + jh * 64) * N_Z);
        #pragma unroll
        for (int p = 0; p < 8; ++p) lv[p] = Lg4[p * 256 + t];
    }

    // ---- class logits (block-uniform -> scalar loads) ----
    float lg[N_COMP];
    #pragma unroll
    for (int k = 0; k < N_COMP; ++k) lg[k] = logits[c * N_COMP + k];

    // ---- selection over this block's slice (4096 samples, 16/thread) ----
    {
        const int ssz   = bs / NSL;          // 4096
        const int sbase = slc * ssz;
        const uint4* y4 = (const uint4*)(y + sbase);
        uint4 yw[4];
        #pragma unroll
        for (int h = 0; h < 4; ++h) yw[h] = y4[4 * t + h];
        #pragma unroll
        for (int h = 0; h < 4; ++h) {
            int ys[4] = {(int)yw[h].x, (int)yw[h].y, (int)yw[h].z, (int)yw[h].w};
            #pragma unroll
            for (int e = 0; e < 4; ++e) {
                if (ys[e] == c) {
                    int s = sbase + t * 16 + h * 4 + e;
                    const float* g = gumbel + ((size_t)c * bs + s) * N_COMP;  // 8-B aligned
                    float2 g01 = *(const float2*)(g + 0);
                    float2 g23 = *(const float2*)(g + 2);
                    float2 g45 = *(const float2*)(g + 4);
                    float2 g67 = *(const float2*)(g + 6);
                    float2 g89 = *(const float2*)(g + 8);
                    float sc[N_COMP] = {
                        g01.x + lg[0], g01.y + lg[1], g23.x + lg[2], g23.y + lg[3],
                        g45.x + lg[4], g45.y + lg[5], g67.x + lg[6], g67.y + lg[7],
                        g89.x + lg[8], g89.y + lg[9] };
                    float best = sc[0];
                    int bi = 0;
                    #pragma unroll
                    for (int k = 1; k < N_COMP; ++k)
                        if (sc[k] > best) { best = sc[k]; bi = k; }  // first-max
                    if (bi == kk) {
                        int p2 = atomicAdd(&cnt, 1);
                        if (p2 < LIST_CAP) list[p2] = s;
                    }
                }
            }
        }
    }

    // ---- store L half into pitched LDS (row = f>>5, col4 = f&31) ----
    #pragma unroll
    for (int p = 0; p < 8; ++p) {
        int f   = p * 256 + t;
        int row = f >> 5;
        int c4  = f & 31;
        bf16x4 b4 = { (__bf16)lv[p].x, (__bf16)lv[p].y, (__bf16)lv[p].z, (__bf16)lv[p].w };
        *(bf16x4*)&Lsb[row * LPITCH + c4 * 4] = b4;
    }
    __syncthreads();   // the only real barrier

    const int n = min(cnt, LIST_CAP);   // ~41 typical per slice
    const int ntiles = (n + 15) >> 4;

    const int wv   = t >> 6;        // wave 0..3
    const int lane = t & 63;
    const int mn   = lane & 15;     // A row / B col / D col index
    const int quad = lane >> 4;     // 0..3

    for (int nt = wv; nt < ntiles; nt += 4) {
        const int nb = nt * 16;
        const int sidx = nb + mn;
        const int samp = list[sidx < n ? sidx : n - 1];   // clamp: dup, masked
        const float* zrow = z + (size_t)samp * N_Z;

        // ---- B-fragments direct from global (L2-hot), cvt fp32->bf16 ----
        bf16x8 bf[4];
        #pragma unroll
        for (int ks = 0; ks < 4; ++ks) {
            float4 z0 = *(const float4*)(zrow + ks * 32 + quad * 8);
            float4 z1 = *(const float4*)(zrow + ks * 32 + quad * 8 + 4);
            bf16x8 b8 = { (__bf16)z0.x, (__bf16)z0.y, (__bf16)z0.z, (__bf16)z0.w,
                          (__bf16)z1.x, (__bf16)z1.y, (__bf16)z1.z, (__bf16)z1.w };
            bf[ks] = b8;
        }

        #pragma unroll
        for (int mt = 0; mt < 4; ++mt) {
            f32x4 acc = {0.f, 0.f, 0.f, 0.f};
            #pragma unroll
            for (int ks = 0; ks < 4; ++ks) {
                bf16x8 af = *(const bf16x8*)&Lsb[(mt * 16 + mn) * LPITCH + ks * 32 + quad * 8];
                acc = __builtin_amdgcn_mfma_f32_16x16x32_bf16(af, bf[ks], acc, 0, 0, 0);
            }
            // lane owns sample col mn, j rows quad*4+0..3
            if (sidx < n) {
                int j0 = jh * 64 + mt * 16 + quad * 4;
                float4 mv = *(const float4*)(m + ck * N_Z + j0);
                float4 o;
                o.x = acc.x + mv.x;
                o.y = acc.y + mv.y;
                o.z = acc.z + mv.z;
                o.w = acc.w + mv.w;
                *(float4*)(out + (size_t)samp * N_Z + j0) = o;
            }
        }
    }
}

extern "C" void kernel_launch(void* const* d_in, const int* in_sizes, int n_in,
                              void* d_out, int out_size, void* d_ws, size_t ws_size,
                              hipStream_t stream)
{
    const float* z      = (const float*)d_in[0];
    const int*   y      = (const int*)d_in[1];
    const float* gumbel = (const float*)d_in[2];
    const float* m      = (const float*)d_in[3];
    const float* L      = (const float*)d_in[4];
    const float* logits = (const float*)d_in[5];
    float* out = (float*)d_out;

    const int bs = in_sizes[0] / N_Z;  // 8192

    k_all<<<dim3(N_CK, 2, NSL), 256, 0, stream>>>(
        z, y, gumbel, m, L, logits, out, bs);
}

// Round 18
// 79.805 us; speedup vs baseline: 1.0637x; 1.0637x over previous
//
#include <hip/hip_runtime.h>

// Forward collapse:
//   c = y[b]; k = argmax_k(logits[c,k] + gumbel[c,b,k]) (first max)
//   x[b,:] = L[c,k] @ z[b,:] + m[c,k,:]
//
// Round 18 = exact revert to Round 16 (best measured: 80.5 us).
// ONE kernel, ZERO cross-block communication. Grid (100 ck, 2 jh, 4 slices)
// = 800 blocks, 256 thr, 18.4 KB LDS. Each block independently:
//   1. prefetches its L-half (8 f4/thread) into regs,
//   2. scans its OWN 2048-sample slice: y preloaded coalesced (2 uint4/thr),
//      gumbel gathered only for y==c candidates (~205), fp32-exact argmax,
//      matches appended to LDS list (~20),
//   3. stores pitched Lsb (conflict-free), ONE barrier,
//   4. mfma_f32_16x16x32_bf16 + fp32 epilogue.
// Slices partition samples -> each output element written exactly once.

#define N_Z 128
#define N_COMP 10
#define N_CLASSES 10
#define N_CK (N_CLASSES * N_COMP)
#define NSL 4            // sample slices
#define LPITCH 136       // bf16 per Lsb row (272 B; 68 dw = 4 mod 32 banks)
#define LIST_CAP 256

typedef __attribute__((ext_vector_type(4))) __bf16 bf16x4;
typedef __attribute__((ext_vector_type(8))) __bf16 bf16x8;
typedef __attribute__((ext_vector_type(4))) float f32x4;

__global__ __launch_bounds__(256, 2) void k_all(
    const float* __restrict__ z, const int* __restrict__ y,
    const float* __restrict__ gumbel, const float* __restrict__ m,
    const float* __restrict__ L, const float* __restrict__ logits,
    float* __restrict__ out, int bs)
{
    const int ck  = blockIdx.x;
    const int jh  = blockIdx.y;              // j range [jh*64, jh*64+64)
    const int slc = blockIdx.z;              // sample slice 0..3
    const int c   = ck / N_COMP;
    const int kk  = ck - c * N_COMP;
    const int t   = threadIdx.x;

    __shared__ __align__(16) __bf16 Lsb[64 * LPITCH];  // 17 KB pitched rows
    __shared__ int list[LIST_CAP];                     // 1 KB
    __shared__ int cnt;

    if (t == 0) cnt = 0;
    __syncthreads();   // cheap: nothing in flight yet

    // ---- prefetch L half into regs ----
    float4 lv[8];
    {
        const float4* Lg4 = (const float4*)(L + ((size_t)ck * N_Z + jh * 64) * N_Z);
        #pragma unroll
        for (int p = 0; p < 8; ++p) lv[p] = Lg4[p * 256 + t];
    }

    // ---- class logits (block-uniform -> scalar loads) ----
    float lg[N_COMP];
    #pragma unroll
    for (int k = 0; k < N_COMP; ++k) lg[k] = logits[c * N_COMP + k];

    // ---- selection over this block's slice (2048 samples, 8/thread) ----
    {
        const int ssz   = bs / NSL;          // 2048
        const int sbase = slc * ssz;
        const uint4* y4 = (const uint4*)(y + sbase);
        uint4 ya = y4[2 * t], yb = y4[2 * t + 1];
        int ys[8] = {(int)ya.x, (int)ya.y, (int)ya.z, (int)ya.w,
                     (int)yb.x, (int)yb.y, (int)yb.z, (int)yb.w};
        #pragma unroll
        for (int e = 0; e < 8; ++e) {
            if (ys[e] == c) {
                int s = sbase + t * 8 + e;
                const float* g = gumbel + ((size_t)c * bs + s) * N_COMP;  // 8-B aligned
                float2 g01 = *(const float2*)(g + 0);
                float2 g23 = *(const float2*)(g + 2);
                float2 g45 = *(const float2*)(g + 4);
                float2 g67 = *(const float2*)(g + 6);
                float2 g89 = *(const float2*)(g + 8);
                float sc[N_COMP] = {
                    g01.x + lg[0], g01.y + lg[1], g23.x + lg[2], g23.y + lg[3],
                    g45.x + lg[4], g45.y + lg[5], g67.x + lg[6], g67.y + lg[7],
                    g89.x + lg[8], g89.y + lg[9] };
                float best = sc[0];
                int bi = 0;
                #pragma unroll
                for (int k = 1; k < N_COMP; ++k)
                    if (sc[k] > best) { best = sc[k]; bi = k; }  // first-max
                if (bi == kk) {
                    int p2 = atomicAdd(&cnt, 1);
                    if (p2 < LIST_CAP) list[p2] = s;
                }
            }
        }
    }

    // ---- store L half into pitched LDS (row = f>>5, col4 = f&31) ----
    #pragma unroll
    for (int p = 0; p < 8; ++p) {
        int f   = p * 256 + t;
        int row = f >> 5;
        int c4  = f & 31;
        bf16x4 b4 = { (__bf16)lv[p].x, (__bf16)lv[p].y, (__bf16)lv[p].z, (__bf16)lv[p].w };
        *(bf16x4*)&Lsb[row * LPITCH + c4 * 4] = b4;
    }
    __syncthreads();   // the only real barrier

    const int n = min(cnt, LIST_CAP);   // ~20 typical per slice
    const int ntiles = (n + 15) >> 4;

    const int wv   = t >> 6;        // wave 0..3
    const int lane = t & 63;
    const int mn   = lane & 15;     // A row / B col / D col index
    const int quad = lane >> 4;     // 0..3

    for (int nt = wv; nt < ntiles; nt += 4) {
        const int nb = nt * 16;
        const int sidx = nb + mn;
        const int samp = list[sidx < n ? sidx : n - 1];   // clamp: dup, masked
        const float* zrow = z + (size_t)samp * N_Z;

        // ---- B-fragments direct from global (L2-hot), cvt fp32->bf16 ----
        bf16x8 bf[4];
        #pragma unroll
        for (int ks = 0; ks < 4; ++ks) {
            float4 z0 = *(const float4*)(zrow + ks * 32 + quad * 8);
            float4 z1 = *(const float4*)(zrow + ks * 32 + quad * 8 + 4);
            bf16x8 b8 = { (__bf16)z0.x, (__bf16)z0.y, (__bf16)z0.z, (__bf16)z0.w,
                          (__bf16)z1.x, (__bf16)z1.y, (__bf16)z1.z, (__bf16)z1.w };
            bf[ks] = b8;
        }

        #pragma unroll
        for (int mt = 0; mt < 4; ++mt) {
            f32x4 acc = {0.f, 0.f, 0.f, 0.f};
            #pragma unroll
            for (int ks = 0; ks < 4; ++ks) {
                bf16x8 af = *(const bf16x8*)&Lsb[(mt * 16 + mn) * LPITCH + ks * 32 + quad * 8];
                acc = __builtin_amdgcn_mfma_f32_16x16x32_bf16(af, bf[ks], acc, 0, 0, 0);
            }
            // lane owns sample col mn, j rows quad*4+0..3
            if (sidx < n) {
                int j0 = jh * 64 + mt * 16 + quad * 4;
                float4 mv = *(const float4*)(m + ck * N_Z + j0);
                float4 o;
                o.x = acc.x + mv.x;
                o.y = acc.y + mv.y;
                o.z = acc.z + mv.z;
                o.w = acc.w + mv.w;
                *(float4*)(out + (size_t)samp * N_Z + j0) = o;
            }
        }
    }
}

extern "C" void kernel_launch(void* const* d_in, const int* in_sizes, int n_in,
                              void* d_out, int out_size, void* d_ws, size_t ws_size,
                              hipStream_t stream)
{
    const float* z      = (const float*)d_in[0];
    const int*   y      = (const int*)d_in[1];
    const float* gumbel = (const float*)d_in[2];
    const float* m      = (const float*)d_in[3];
    const float* L      = (const float*)d_in[4];
    const float* logits = (const float*)d_in[5];
    float* out = (float*)d_out;

    const int bs = in_sizes[0] / N_Z;  // 8192

    k_all<<<dim3(N_CK, 2, NSL), 256, 0, stream>>>(
        z, y, gumbel, m, L, logits, out, bs);
}